// Round 1
// baseline (47.315 us; speedup 1.0000x reference)
//
#include <hip/hip_runtime.h>
#include <hip/hip_bf16.h>
#include <math.h>

// Problem constants (from reference): H=1024, E=48, R=32
#define Hh 1024
#define Ee 48
#define Rr 32
#define NTRIP (Ee*Ee*Rr)   // 73728
#define NROWS 128          // 48 A-rows + 32 R-rows + 48 B-rows
#define HS 8               // h-split for phase 2
#define HRANGE (Hh/HS)     // 128
#define PITCH 132          // LDS row pitch (floats): 128+4, 16B-aligned rows

// ---------------- Kernel 1: partial GEMMs  T_part[fs][row][h] ----------------
// grid (4 h-tiles, 8 row-tiles, FS f-splits), block 256.
// Each block: 16 rows x 256 h, K-chunk fcount. emb tile staged in LDS.
__global__ __launch_bounds__(256) void k1_gemm(const float* __restrict__ ent,
                                               const float* __restrict__ rel,
                                               const float* __restrict__ W1,
                                               float* __restrict__ Ppart,
                                               int fcount) {
    extern __shared__ float se[];          // [16][fcount]
    const int ht = blockIdx.x;             // 0..3
    const int rt = blockIdx.y;             // 0..7
    const int fs = blockIdx.z;             // 0..FS-1
    const int row0 = rt * 16;
    const int tid = threadIdx.x;

    const float* emb; int foff;
    if (row0 < 48)      { emb = ent + row0 * Hh;        foff = 0;      }
    else if (row0 < 80) { emb = rel + (row0 - 48) * Hh; foff = Hh;     }
    else                { emb = ent + (row0 - 80) * Hh; foff = 2 * Hh; }

    const int f0 = fs * fcount;
    // stage emb tile (16 rows x fcount), coalesced
    for (int r = 0; r < 16; ++r)
        for (int f = tid; f < fcount; f += 256)
            se[r * fcount + f] = emb[r * Hh + f0 + f];
    __syncthreads();

    const int h = ht * 256 + tid;
    float acc[16];
#pragma unroll
    for (int r = 0; r < 16; ++r) acc[r] = 0.f;

    const float* w1p = W1 + (size_t)(foff + f0) * Hh + h;
    for (int f = 0; f < fcount; f += 4) {
        const float w0 = w1p[(size_t)(f + 0) * Hh];
        const float w1v = w1p[(size_t)(f + 1) * Hh];
        const float w2v = w1p[(size_t)(f + 2) * Hh];
        const float w3v = w1p[(size_t)(f + 3) * Hh];
#pragma unroll
        for (int r = 0; r < 16; ++r) {
            const float4 e4 = *reinterpret_cast<const float4*>(&se[r * fcount + f]);
            acc[r] = fmaf(e4.x, w0, acc[r]);
            acc[r] = fmaf(e4.y, w1v, acc[r]);
            acc[r] = fmaf(e4.z, w2v, acc[r]);
            acc[r] = fmaf(e4.w, w3v, acc[r]);
        }
    }
    float* outp = Ppart + ((size_t)fs * NROWS + row0) * Hh + h;
#pragma unroll
    for (int r = 0; r < 16; ++r) outp[(size_t)r * Hh] = acc[r];
}

// ---------------- Kernel 1b: reduce f-splits, fold b1 into rel rows ----------
__global__ __launch_bounds__(256) void k1b_reduce(const float* __restrict__ Ppart,
                                                  const float* __restrict__ b1,
                                                  float* __restrict__ T, int FS) {
    const int idx = blockIdx.x * 256 + threadIdx.x;   // < 128*1024
    const int r = idx >> 10, h = idx & 1023;
    float s = 0.f;
    for (int fs = 0; fs < FS; ++fs) s += Ppart[(size_t)fs * (NROWS * Hh) + idx];
    if (r >= 48 && r < 80) s += b1[h];
    T[idx] = s;
}

// ---------------- Kernel 2: triplet partial logits ---------------------------
// grid (12 i-tiles, 3 j-tiles, 8 h-slices), block 256 (4 waves).
// wave = i within tile; lane: jg = lane&3, kg = lane>>2.
// per lane: 4 j (jg+4*tj) x 2 k (kg+16*tk) = 8 triplet partial sums.
__global__ __launch_bounds__(256) void k2_triplets(const float* __restrict__ T,
                                                   const float* __restrict__ W2,
                                                   float* __restrict__ Lpart) {
    __shared__ float sm[52 * PITCH + HRANGE];  // A(4) R(32) B(16) rows + W2
    const int tid = threadIdx.x;
    const int i0 = blockIdx.x * 4;
    const int j0 = blockIdx.y * 16;
    const int h0 = blockIdx.z * HRANGE;

    // stage 52 rows x HRANGE from T (coalesced global, conflict-free LDS)
    for (int idx = tid; idx < 52 * HRANGE; idx += 256) {
        const int rsel = idx >> 7;      // /HRANGE
        const int h = idx & (HRANGE - 1);
        int g;
        if (rsel < 4)       g = i0 + rsel;            // A rows (subject)
        else if (rsel < 36) g = 48 + (rsel - 4);      // R rows
        else                g = 80 + j0 + (rsel - 36);// B rows (object)
        sm[rsel * PITCH + h] = T[g * Hh + h0 + h];
    }
    if (tid < HRANGE) sm[52 * PITCH + tid] = W2[h0 + tid];
    __syncthreads();

    const int wave = tid >> 6;
    const int lane = tid & 63;
    const int jg = lane & 3;
    const int kg = lane >> 2;

    const float* pa = sm + wave * PITCH;
    const float* pw = sm + 52 * PITCH;
    const float* pr0 = sm + (4 + kg) * PITCH;        // k = kg
    const float* pr1 = sm + (4 + kg + 16) * PITCH;   // k = kg+16
    const float* pb0 = sm + (36 + jg) * PITCH;       // j rows jg+4*tj

    float acc[4][2];
#pragma unroll
    for (int a = 0; a < 4; ++a) { acc[a][0] = 0.f; acc[a][1] = 0.f; }

    union F4 { float4 v; float f[4]; };
    for (int h4 = 0; h4 < HRANGE; h4 += 4) {
        F4 av, wv, r0, r1, bv[4];
        av.v = *reinterpret_cast<const float4*>(pa + h4);
        wv.v = *reinterpret_cast<const float4*>(pw + h4);
        r0.v = *reinterpret_cast<const float4*>(pr0 + h4);
        r1.v = *reinterpret_cast<const float4*>(pr1 + h4);
#pragma unroll
        for (int tj = 0; tj < 4; ++tj)
            bv[tj].v = *reinterpret_cast<const float4*>(pb0 + tj * 4 * PITCH + h4);
#pragma unroll
        for (int c = 0; c < 4; ++c) {
            const float a = av.f[c], w = wv.f[c];
            const float p0 = a + r0.f[c];
            const float p1 = a + r1.f[c];
#pragma unroll
            for (int tj = 0; tj < 4; ++tj) {
                const float bb = bv[tj].f[c];
                float v0 = p0 + bb; v0 = v0 > 0.f ? v0 : 0.f;
                acc[tj][0] = fmaf(v0, w, acc[tj][0]);
                float v1 = p1 + bb; v1 = v1 > 0.f ? v1 : 0.f;
                acc[tj][1] = fmaf(v1, w, acc[tj][1]);
            }
        }
    }

    float* lp = Lpart + (size_t)blockIdx.z * NTRIP;
    const int i_ = i0 + wave;
#pragma unroll
    for (int tj = 0; tj < 4; ++tj) {
        const int j_ = j0 + jg + 4 * tj;
#pragma unroll
        for (int tk = 0; tk < 2; ++tk) {
            const int k_ = kg + 16 * tk;
            lp[(i_ * Ee + j_) * Rr + k_] = acc[tj][tk];
        }
    }
}

// ---------------- Kernel 3: reduce h-slices, sigmoid, mask -------------------
__global__ __launch_bounds__(256) void k3_final(const float* __restrict__ Lpart,
                                                const float* __restrict__ b2,
                                                const int* __restrict__ starts,
                                                const int* __restrict__ maxd,
                                                float* __restrict__ out) {
    const int idx = blockIdx.x * 256 + threadIdx.x;   // < 73728
    float s = b2[0];
#pragma unroll
    for (int z = 0; z < HS; ++z) s += Lpart[(size_t)z * NTRIP + idx];
    const int ij = idx >> 5;          // /32
    const int j = ij % Ee;
    const int i = ij / Ee;
    const float sc = 1.f / (1.f + expf(-s));
    int di = starts[i] - starts[j]; if (di < 0) di = -di;
    const bool m = (i != j) && (di <= maxd[0]);
    out[idx] = m ? sc : 0.f;
}

extern "C" void kernel_launch(void* const* d_in, const int* in_sizes, int n_in,
                              void* d_out, int out_size, void* d_ws, size_t ws_size,
                              hipStream_t stream) {
    const float* ent    = (const float*)d_in[0];
    const float* rel    = (const float*)d_in[1];
    const float* W1     = (const float*)d_in[2];
    const float* b1     = (const float*)d_in[3];
    const float* W2     = (const float*)d_in[4];
    const float* b2     = (const float*)d_in[5];
    const int*   starts = (const int*)d_in[6];
    const int*   maxd   = (const int*)d_in[7];
    float* out = (float*)d_out;
    char* ws = (char*)d_ws;

    const size_t lpartB = (size_t)HS * NTRIP * 4;          // 2359296
    int FS;
    {
        const size_t need8 = (size_t)8 * NROWS * Hh * 4 + (size_t)NROWS * Hh * 4; // 4.5MB
        FS = (ws_size >= need8) ? 8 : 2;
    }
    const size_t ppartB = (size_t)FS * NROWS * Hh * 4;
    const size_t regionA = (ppartB > lpartB) ? ppartB : lpartB;

    float* Ppart = (float*)ws;               // phase-1 partials (consumed by k1b)
    float* Lpart = (float*)ws;               // phase-2 partials (reuses region A)
    float* T     = (float*)(ws + regionA);   // combined table [128][1024]

    const int fcount = Hh / FS;
    k1_gemm<<<dim3(4, 8, FS), 256, 16 * fcount * 4, stream>>>(ent, rel, W1, Ppart, fcount);
    k1b_reduce<<<(NROWS * Hh) / 256, 256, 0, stream>>>(Ppart, b1, T, FS);
    k2_triplets<<<dim3(12, 3, 8), 256, 0, stream>>>(T, W2, Lpart);
    k3_final<<<NTRIP / 256, 256, 0, stream>>>(Lpart, b2, starts, maxd, out);
}